// Round 16
// baseline (192.789 us; speedup 1.0000x reference)
//
#include <hip/hip_runtime.h>

#define N_NODES 20000
#define N_REL 200
#define N_EDGES 200000
#define DIM 128
#define T_STEPS 8
#define N_TILES (N_NODES / 16)              // 1250
#define KEYS (N_NODES * T_STEPS)            // 160000 (dst,t) segments
#define SCAN_N (KEYS + 1)                   // 160001
#define SCAN_BLKS ((SCAN_N + 1023) / 1024)  // 157

typedef short short8 __attribute__((ext_vector_type(8)));
typedef float f32x4 __attribute__((ext_vector_type(4)));

static __device__ __forceinline__ unsigned short f2bf(float f) {
  union { float f; unsigned u; } v; v.f = f;
  unsigned r = v.u + 0x7fffu + ((v.u >> 16) & 1u);   // RNE
  return (unsigned short)(r >> 16);
}
// packed f32x2 -> bf16x2 (RNE), 1 instruction
static __device__ __forceinline__ unsigned cvt_pk_bf16(float lo, float hi) {
  unsigned r;
  asm("v_cvt_pk_bf16_f32 %0, %1, %2" : "=v"(r) : "v"(lo), "v"(hi));
  return r;
}
static __device__ __forceinline__ float fast_tanh(float x) {
  float e = __expf(2.f * x);           // inf-safe: x>>0 -> 1, x<<0 -> -1
  return 1.f - 2.f / (e + 1.f);
}
static __device__ __forceinline__ float fast_sig(float x) {
  return 1.f / (1.f + __expf(-x));
}

// ---------------------------------------------------------------------------
// Repack the five 128x128 fp32 weight matrices (row-major W[k][n]) into bf16
// MFMA B-fragment order: pack[m][((nt*4+ks)*64+lane)*8+j] = bf16(W[k][n]),
// n = nt*16 + (lane&15), k = ks*32 + (lane>>4)*8 + j.
// Slots: 0=Wenc 1=Wz 2=Uz 3=Wh 4=Uh.
// ---------------------------------------------------------------------------
__global__ void repack5(const float* __restrict__ w0,
                        const float* __restrict__ w1,
                        const float* __restrict__ w2,
                        const float* __restrict__ w3,
                        const float* __restrict__ w4,
                        unsigned short* __restrict__ pack) {
  int i = blockIdx.x * blockDim.x + threadIdx.x;
  if (i >= 5 * 16384) return;
  int m = i >> 14, r = i & 16383;
  int j = r & 7, lane = (r >> 3) & 63, ks = (r >> 9) & 3, nt = (r >> 11) & 7;
  int n = nt * 16 + (lane & 15);
  int k = ks * 32 + (lane >> 4) * 8 + j;
  const float* w = (m == 0) ? w0 : (m == 1) ? w1 : (m == 2) ? w2
                 : (m == 3) ? w3 : w4;
  pack[i] = f2bf(w[k * DIM + n]);
}

// ----------------- CSR build: bucket by key = dst*8 + t --------------------
__global__ void hist_k(const int* __restrict__ dst, const int* __restrict__ etime,
                       int* __restrict__ counts) {
  int i = blockIdx.x * blockDim.x + threadIdx.x;
  if (i >= N_EDGES) return;
  atomicAdd(&counts[dst[i] * T_STEPS + etime[i]], 1);
}

__global__ void scan1_k(const int* __restrict__ counts,
                        int* __restrict__ base, int* __restrict__ bsum) {
  __shared__ int ls[256];
  int tid = threadIdx.x;
  int i0 = blockIdx.x * 1024 + tid * 4;
  int v[4], ts = 0;
#pragma unroll
  for (int r = 0; r < 4; r++) {
    v[r] = (i0 + r < SCAN_N) ? counts[i0 + r] : 0;
    ts += v[r];
  }
  ls[tid] = ts; __syncthreads();
#pragma unroll
  for (int off = 1; off < 256; off <<= 1) {
    int x = (tid >= off) ? ls[tid - off] : 0;
    __syncthreads(); ls[tid] += x; __syncthreads();
  }
  int run = ls[tid] - ts;
  if (tid == 255) bsum[blockIdx.x] = ls[255];
#pragma unroll
  for (int r = 0; r < 4; r++) {
    if (i0 + r < SCAN_N) base[i0 + r] = run;
    run += v[r];
  }
}

__global__ void scan2_k(int* __restrict__ bsum) {
  __shared__ int ls[256];
  int tid = threadIdx.x;
  int v = (tid < SCAN_BLKS) ? bsum[tid] : 0;
  ls[tid] = v; __syncthreads();
#pragma unroll
  for (int off = 1; off < 256; off <<= 1) {
    int x = (tid >= off) ? ls[tid - off] : 0;
    __syncthreads(); ls[tid] += x; __syncthreads();
  }
  if (tid < SCAN_BLKS) bsum[tid] = ls[tid] - v;
}

// ep2 = {src | rel<<15 | t<<23, weight bits}  (t also implicit in segment;
// carried in spare bits so the gather can walk a node's full range).
// scan3 folded in: absolute position = base[key] + bsum[key>>10] + cursor++.
__global__ void fill_k(const int* __restrict__ src, const int* __restrict__ dst,
                       const int* __restrict__ etype, const int* __restrict__ etime,
                       const float* __restrict__ ew,
                       const int* __restrict__ base, const int* __restrict__ bsum,
                       int* __restrict__ cursor, uint2* __restrict__ ep2) {
  int i = blockIdx.x * blockDim.x + threadIdx.x;
  if (i >= N_EDGES) return;
  int t = etime[i];
  int key = dst[i] * T_STEPS + t;
  int pos = base[key] + bsum[key >> 10] + atomicAdd(&cursor[key], 1);
  uint2 e;
  e.x = (unsigned)src[i] | ((unsigned)etype[i] << 15) | ((unsigned)t << 23);
  e.y = __float_as_uint(ew[i]);
  ep2[pos] = e;
}

// ---- phase-A edge helpers: SCALAR metadata (wave-uniform), named accs ----
// Clamped index keeps all loads in-bounds (any ep2 slot is a real edge, so
// src<20000, rel<200 even for invalid slots); invalid edges get w=0 via a
// scalar cselect -> their contribution is +0 (bit-exact no-op).
#define EDGE_LOAD(jj, valid, M0, M1, TT)                                      \
  int TT; float M0, M1;                                                       \
  {                                                                           \
    int j_ = (jj) < (N_EDGES - 1) ? (jj) : (N_EDGES - 1);                     \
    uint2 e_ = ep2[j_];                                                       \
    unsigned x_ = (unsigned)__builtin_amdgcn_readfirstlane((int)e_.x);        \
    float w_ = __uint_as_float(                                               \
        (unsigned)__builtin_amdgcn_readfirstlane((int)e_.y));                 \
    w_ = (valid) ? w_ : 0.f;                                                  \
    int s_ = (int)(x_ & 0x7fffu), r_ = (int)((x_ >> 15) & 0xffu);             \
    TT = (int)((x_ >> 23) & 7u);                                              \
    float2 sv_ = *(const float2*)(nemb + (size_t)s_ * DIM + 2 * lane);        \
    float2 rv_ = *(const float2*)(remb + (size_t)r_ * DIM + 2 * lane);        \
    M0 = sv_.x * rv_.x * w_;                                                  \
    M1 = sv_.y * rv_.y * w_;                                                  \
  }

// scalar-branch accumulate: TT is wave-uniform (SGPR) -> compile-time-indexed
// named accumulators, 2 v_add per edge, decode on the scalar pipe.
#define ACC_SWITCH(TT, AXP, AYP, M0, M1)                                      \
  switch (TT) {                                                               \
    case 0: AXP##0 += M0; AYP##0 += M1; break;                                \
    case 1: AXP##1 += M0; AYP##1 += M1; break;                                \
    case 2: AXP##2 += M0; AYP##2 += M1; break;                                \
    case 3: AXP##3 += M0; AYP##3 += M1; break;                                \
    case 4: AXP##4 += M0; AYP##4 += M1; break;                                \
    case 5: AXP##5 += M0; AYP##5 += M1; break;                                \
    case 6: AXP##6 += M0; AYP##6 += M1; break;                                \
    default: AXP##7 += M0; AYP##7 += M1; break;                               \
  }

#define DECL8(P) float P##0 = 0.f, P##1 = 0.f, P##2 = 0.f, P##3 = 0.f,        \
                       P##4 = 0.f, P##5 = 0.f, P##6 = 0.f, P##7 = 0.f

#define STROW(TT, NL, AX, AY)                                                 \
  ((unsigned*)&aggL[((TT) * 16 + (NL)) * 136])[lane] = cvt_pk_bf16(AX, AY)

#define STROW8(NL, AXP, AYP)                                                  \
  STROW(0, NL, AXP##0, AYP##0); STROW(1, NL, AXP##1, AYP##1);                 \
  STROW(2, NL, AXP##2, AYP##2); STROW(3, NL, AXP##3, AYP##3);                 \
  STROW(4, NL, AXP##4, AYP##4); STROW(5, NL, AXP##5, AYP##5);                 \
  STROW(6, NL, AXP##6, AYP##6); STROW(7, NL, AXP##7, AYP##7)

// ---------------------------------------------------------------------------
// Fully-fused GATHER + encoder + GRU recurrence. One block per 16-node tile,
// 8 waves. Exact R15 phases A/B; phase C switched to the R9 form (t=0 S-path
// skip + 4 independent MFMA chains) -- R9 measured it neutral, but that run
// carried a phase-A spill regression (+10MB scratch) that masked it; on this
// spill-free base it removes 8 MFMAs + 4 ds_writes + 4 ds_reads + 2 cvt_pk
// at t=0 (bit-exact: S==0, MFMA with A=0 adds +0; R9's passing run printed
// absmax 0.00831604 with exactly this arithmetic) and halves every step's
// dependent MFMA chain (8 -> 4) for denser issue inside the barrier convoy.
// Phase A (gather): wave-uniform scalar decode (R14) + 4 edges/node/iter
//   quad walk (R15): 8 meta chains + 16 row loads in flight; branchless
//   validity via scalar cselect (w=0). Spill tripwire: WRITE_SIZE == 10000.
// Phase B (encoder, hoisted): 32 MFMAs vs wenc -> hpk[t] packed bf16.
// Phase C (recurrence): per step t: H[t] (and S for t>0) -> double-buffered
//   LDS (stride 136), ONE barrier, re-read as A-frags; zh/ch (biased,
//   H-driven) and zs/cs (zero-init, S-driven, t>0 only) accumulate in 4
//   independent 4-long chains, combined by one fp32 add; gates; update.
// MFMA 16x16x32_bf16 layouts (HW-verified): A: m=lane&15,k=quad*8+j;
// B: n=lane&15,k=quad*8+j;  C/D: col=lane&15, row=quad*4+reg.
// Double-buffer WAR safety: W(t) B(t) R(t) W(t+1)...: a wave at W(t+2)
// (overwrite of buffer t&1) passed B(t+1); every wave at B(t+1) completed
// R(t). Sb[1] first written at t=1 and first read at t=1 after the barrier;
// Sb[0] first written t=2, read t=2 -> no uninitialized reads. aggL is
// written only in phase A (barrier-protected) and read-only afterwards.
// ---------------------------------------------------------------------------
__launch_bounds__(512, 4)
__global__ void fused_recur(const int* __restrict__ base,
                            const int* __restrict__ bsum,
                            const uint2* __restrict__ ep2,
                            const float* __restrict__ nemb,
                            const float* __restrict__ remb,
                            const unsigned short* __restrict__ pack,
                            const float* __restrict__ bz,
                            const float* __restrict__ bh,
                            float* __restrict__ out) {
  __shared__ unsigned short aggL[T_STEPS * 16 * 136];   // 34816 B
  __shared__ unsigned short Hb[2][16 * 136];            //  8704 B
  __shared__ unsigned short Sb[2][16 * 136];            //  8704 B
  int lane = threadIdx.x & 63;
  int nt = threadIdx.x >> 6;        // wave id: owns nodes {2nt,2nt+1} / col tile nt
  int q = lane >> 4, l15 = lane & 15;
  int tile = blockIdx.x;
  int row0 = tile * 16;
  int c = nt * 16 + l15;

  // ---- Phase A: scalar-decoded, branchless-validity, 8-chain quad walk ----
  {
    int kb0 = (row0 + nt * 2) * T_STEPS;
    int kb1 = kb0 + T_STEPS;
    int ke1 = kb1 + T_STEPS;
    int i0 = __builtin_amdgcn_readfirstlane(base[kb0] + bsum[kb0 >> 10]);
    int e0 = __builtin_amdgcn_readfirstlane(base[kb1] + bsum[kb1 >> 10]);
    int i1 = e0;                               // contiguous key ranges
    int e1 = __builtin_amdgcn_readfirstlane(base[ke1] + bsum[ke1 >> 10]);

    DECL8(ax0_); DECL8(ay0_); DECL8(ax1_); DECL8(ay1_);

    while (i0 < e0 || i1 < e1) {               // scalar control
      bool v00 = i0 < e0,     v01 = i0 + 1 < e0;
      bool v02 = i0 + 2 < e0, v03 = i0 + 3 < e0;
      bool v10 = i1 < e1,     v11 = i1 + 1 < e1;
      bool v12 = i1 + 2 < e1, v13 = i1 + 3 < e1;
      EDGE_LOAD(i0,     v00, m0a, m1a, ta);
      EDGE_LOAD(i0 + 1, v01, m0b, m1b, tb);
      EDGE_LOAD(i0 + 2, v02, m0c, m1c, tc);
      EDGE_LOAD(i0 + 3, v03, m0d, m1d, td);
      EDGE_LOAD(i1,     v10, m0e, m1e, te);
      EDGE_LOAD(i1 + 1, v11, m0f, m1f, tf);
      EDGE_LOAD(i1 + 2, v12, m0g, m1g, tg);
      EDGE_LOAD(i1 + 3, v13, m0h, m1h, th);
      ACC_SWITCH(ta, ax0_, ay0_, m0a, m1a);
      ACC_SWITCH(tb, ax0_, ay0_, m0b, m1b);
      ACC_SWITCH(tc, ax0_, ay0_, m0c, m1c);
      ACC_SWITCH(td, ax0_, ay0_, m0d, m1d);
      ACC_SWITCH(te, ax1_, ay1_, m0e, m1e);
      ACC_SWITCH(tf, ax1_, ay1_, m0f, m1f);
      ACC_SWITCH(tg, ax1_, ay1_, m0g, m1g);
      ACC_SWITCH(th, ax1_, ay1_, m0h, m1h);
      i0 = (i0 + 4 < e0) ? i0 + 4 : e0;
      i1 = (i1 + 4 < e1) ? i1 + 4 : e1;
    }

    int nl0 = nt * 2, nl1 = nt * 2 + 1;
    STROW8(nl0, ax0_, ay0_);
    STROW8(nl1, ax1_, ay1_);
  }
  __syncthreads();

  // ---- Phase B: encoder for ALL steps: H[t](:, nt-cols) as packed bf16 ----
  unsigned hpk[T_STEPS][2];
  {
    short8 wenc[4];
#pragma unroll
    for (int ks = 0; ks < 4; ks++)
      wenc[ks] = *(const short8*)(pack + ((nt * 4 + ks) * 64 + lane) * 8);
#pragma unroll
    for (int t = 0; t < T_STEPS; t++) {
      f32x4 acch = (f32x4){0.f, 0.f, 0.f, 0.f};
#pragma unroll
      for (int ks = 0; ks < 4; ks++) {
        short8 aA = *(const short8*)&aggL[(t * 16 + l15) * 136 + ks * 32 + q * 8];
        acch = __builtin_amdgcn_mfma_f32_16x16x32_bf16(aA, wenc[ks], acch, 0, 0, 0);
      }
      hpk[t][0] = cvt_pk_bf16(fast_tanh(acch[0]), fast_tanh(acch[1]));
      hpk[t][1] = cvt_pk_bf16(fast_tanh(acch[2]), fast_tanh(acch[3]));
    }
  }

  // recurrence weight B-fragments for this wave's nt
  short8 wz[4], uz[4], wh[4], uh[4];
#pragma unroll
  for (int ks = 0; ks < 4; ks++) {
    int fo = ((nt * 4 + ks) * 64 + lane) * 8;
    wz[ks] = *(const short8*)(pack + 16384 * 1 + fo);
    uz[ks] = *(const short8*)(pack + 16384 * 2 + fo);
    wh[ks] = *(const short8*)(pack + 16384 * 3 + fo);
    uh[ks] = *(const short8*)(pack + 16384 * 4 + fo);
  }
  float bzv = bz[c];
  float bhv = bh[c];

  f32x4 stC = (f32x4){0.f, 0.f, 0.f, 0.f};

  // ---- Phase C: GRU recurrence (4-chain ILP, t=0 S-path skipped) ----
#pragma unroll
  for (int t = 0; t < T_STEPS; t++) {
    unsigned short* hB = Hb[t & 1];
    unsigned short* sB = Sb[t & 1];
    hB[(q * 4 + 0) * 136 + c] = (unsigned short)hpk[t][0];
    hB[(q * 4 + 1) * 136 + c] = (unsigned short)(hpk[t][0] >> 16);
    hB[(q * 4 + 2) * 136 + c] = (unsigned short)hpk[t][1];
    hB[(q * 4 + 3) * 136 + c] = (unsigned short)(hpk[t][1] >> 16);
    if (t > 0) {
      unsigned s01 = cvt_pk_bf16(stC[0], stC[1]);
      unsigned s23 = cvt_pk_bf16(stC[2], stC[3]);
      sB[(q * 4 + 0) * 136 + c] = (unsigned short)s01;
      sB[(q * 4 + 1) * 136 + c] = (unsigned short)(s01 >> 16);
      sB[(q * 4 + 2) * 136 + c] = (unsigned short)s23;
      sB[(q * 4 + 3) * 136 + c] = (unsigned short)(s23 >> 16);
    }
    __syncthreads();

    short8 hA[4], sA[4];
#pragma unroll
    for (int ks = 0; ks < 4; ks++)
      hA[ks] = *(const short8*)&hB[l15 * 136 + ks * 32 + q * 8];
    if (t > 0) {
#pragma unroll
      for (int ks = 0; ks < 4; ks++)
        sA[ks] = *(const short8*)&sB[l15 * 136 + ks * 32 + q * 8];
    }

    f32x4 zh = (f32x4){bzv, bzv, bzv, bzv};
    f32x4 ch = (f32x4){bhv, bhv, bhv, bhv};
    f32x4 zs = (f32x4){0.f, 0.f, 0.f, 0.f};
    f32x4 cs = (f32x4){0.f, 0.f, 0.f, 0.f};
#pragma unroll
    for (int ks = 0; ks < 4; ks++) {
      zh = __builtin_amdgcn_mfma_f32_16x16x32_bf16(hA[ks], wz[ks], zh, 0, 0, 0);
      ch = __builtin_amdgcn_mfma_f32_16x16x32_bf16(hA[ks], wh[ks], ch, 0, 0, 0);
    }
    if (t > 0) {
#pragma unroll
      for (int ks = 0; ks < 4; ks++) {
        zs = __builtin_amdgcn_mfma_f32_16x16x32_bf16(sA[ks], uz[ks], zs, 0, 0, 0);
        cs = __builtin_amdgcn_mfma_f32_16x16x32_bf16(sA[ks], uh[ks], cs, 0, 0, 0);
      }
    }
#pragma unroll
    for (int r = 0; r < 4; r++) {
      float z = fast_sig(zh[r] + zs[r]);
      float cc = fast_tanh(ch[r] + cs[r]);
      stC[r] = (1.f - z) * stC[r] + z * cc;
    }
  }

  // final state -> out (fp32, C-layout positions)
#pragma unroll
  for (int r = 0; r < 4; r++)
    out[(size_t)(row0 + q * 4 + r) * DIM + c] = stC[r];
}

extern "C" void kernel_launch(void* const* d_in, const int* in_sizes, int n_in,
                              void* d_out, int out_size, void* d_ws, size_t ws_size,
                              hipStream_t stream) {
  const int* eidx  = (const int*)d_in[0];
  const int* src   = eidx;
  const int* dst   = eidx + N_EDGES;
  const int* etype = (const int*)d_in[1];
  const int* etime = (const int*)d_in[2];
  const float* ew   = (const float*)d_in[3];
  const float* nemb = (const float*)d_in[4];
  const float* remb = (const float*)d_in[5];
  const float* Wenc = (const float*)d_in[6];
  const float* Wz   = (const float*)d_in[7];
  const float* Uz   = (const float*)d_in[8];
  const float* Wh   = (const float*)d_in[9];
  const float* Uh   = (const float*)d_in[10];
  const float* bz   = (const float*)d_in[11];
  const float* bh   = (const float*)d_in[12];
  // d_in[13] = num_times (constant 8 for this problem's fixed shapes)

  // ws layout
  int* counts = (int*)d_ws;                                        // SCAN_N
  int* cursor = counts + SCAN_N;                                   // KEYS
  int* bsum   = cursor + KEYS;                                     // 256
  int* base   = bsum + 256;                                        // SCAN_N
  uint2* ep2  = (uint2*)(base + ((SCAN_N + 1) & ~1));              // E, 8B-aligned
  unsigned short* pack = (unsigned short*)(ep2 + N_EDGES);         // 5*16384
  float* outp = (float*)d_out;

  hipMemsetAsync(counts, 0, (size_t)(SCAN_N + KEYS) * sizeof(int), stream);
  repack5<<<(5 * 16384 + 255) / 256, 256, 0, stream>>>(Wenc, Wz, Uz, Wh, Uh, pack);
  hist_k<<<(N_EDGES + 255) / 256, 256, 0, stream>>>(dst, etime, counts);
  scan1_k<<<SCAN_BLKS, 256, 0, stream>>>(counts, base, bsum);
  scan2_k<<<1, 256, 0, stream>>>(bsum);
  fill_k<<<(N_EDGES + 255) / 256, 256, 0, stream>>>(src, dst, etype, etime, ew,
                                                    base, bsum, cursor, ep2);
  fused_recur<<<N_TILES, 512, 0, stream>>>(base, bsum, ep2, nemb, remb,
                                           pack, bz, bh, outp);
}

// Round 17
// 191.178 us; speedup vs baseline: 1.0084x; 1.0084x over previous
//
#include <hip/hip_runtime.h>

#define N_NODES 20000
#define N_REL 200
#define N_EDGES 200000
#define DIM 128
#define T_STEPS 8
#define N_TILES (N_NODES / 16)              // 1250
#define KEYS (N_NODES * T_STEPS)            // 160000 (dst,t) segments
#define SCAN_N (KEYS + 1)                   // 160001
#define SCAN_BLKS ((SCAN_N + 1023) / 1024)  // 157

typedef short short8 __attribute__((ext_vector_type(8)));
typedef float f32x4 __attribute__((ext_vector_type(4)));

static __device__ __forceinline__ unsigned short f2bf(float f) {
  union { float f; unsigned u; } v; v.f = f;
  unsigned r = v.u + 0x7fffu + ((v.u >> 16) & 1u);   // RNE
  return (unsigned short)(r >> 16);
}
// packed f32x2 -> bf16x2 (RNE), 1 instruction
static __device__ __forceinline__ unsigned cvt_pk_bf16(float lo, float hi) {
  unsigned r;
  asm("v_cvt_pk_bf16_f32 %0, %1, %2" : "=v"(r) : "v"(lo), "v"(hi));
  return r;
}
static __device__ __forceinline__ float fast_tanh(float x) {
  float e = __expf(2.f * x);           // inf-safe: x>>0 -> 1, x<<0 -> -1
  return 1.f - 2.f / (e + 1.f);
}
static __device__ __forceinline__ float fast_sig(float x) {
  return 1.f / (1.f + __expf(-x));
}

// ---------------------------------------------------------------------------
// Repack the five 128x128 fp32 weight matrices (row-major W[k][n]) into bf16
// MFMA B-fragment order: pack[m][((nt*4+ks)*64+lane)*8+j] = bf16(W[k][n]),
// n = nt*16 + (lane&15), k = ks*32 + (lane>>4)*8 + j.
// Slots: 0=Wenc 1=Wz 2=Uz 3=Wh 4=Uh.
// ---------------------------------------------------------------------------
__global__ void repack5(const float* __restrict__ w0,
                        const float* __restrict__ w1,
                        const float* __restrict__ w2,
                        const float* __restrict__ w3,
                        const float* __restrict__ w4,
                        unsigned short* __restrict__ pack) {
  int i = blockIdx.x * blockDim.x + threadIdx.x;
  if (i >= 5 * 16384) return;
  int m = i >> 14, r = i & 16383;
  int j = r & 7, lane = (r >> 3) & 63, ks = (r >> 9) & 3, nt = (r >> 11) & 7;
  int n = nt * 16 + (lane & 15);
  int k = ks * 32 + (lane >> 4) * 8 + j;
  const float* w = (m == 0) ? w0 : (m == 1) ? w1 : (m == 2) ? w2
                 : (m == 3) ? w3 : w4;
  pack[i] = f2bf(w[k * DIM + n]);
}

// ----------------- CSR build: bucket by key = dst*8 + t --------------------
__global__ void hist_k(const int* __restrict__ dst, const int* __restrict__ etime,
                       int* __restrict__ counts) {
  int i = blockIdx.x * blockDim.x + threadIdx.x;
  if (i >= N_EDGES) return;
  atomicAdd(&counts[dst[i] * T_STEPS + etime[i]], 1);
}

__global__ void scan1_k(const int* __restrict__ counts,
                        int* __restrict__ base, int* __restrict__ bsum) {
  __shared__ int ls[256];
  int tid = threadIdx.x;
  int i0 = blockIdx.x * 1024 + tid * 4;
  int v[4], ts = 0;
#pragma unroll
  for (int r = 0; r < 4; r++) {
    v[r] = (i0 + r < SCAN_N) ? counts[i0 + r] : 0;
    ts += v[r];
  }
  ls[tid] = ts; __syncthreads();
#pragma unroll
  for (int off = 1; off < 256; off <<= 1) {
    int x = (tid >= off) ? ls[tid - off] : 0;
    __syncthreads(); ls[tid] += x; __syncthreads();
  }
  int run = ls[tid] - ts;
  if (tid == 255) bsum[blockIdx.x] = ls[255];
#pragma unroll
  for (int r = 0; r < 4; r++) {
    if (i0 + r < SCAN_N) base[i0 + r] = run;
    run += v[r];
  }
}

__global__ void scan2_k(int* __restrict__ bsum) {
  __shared__ int ls[256];
  int tid = threadIdx.x;
  int v = (tid < SCAN_BLKS) ? bsum[tid] : 0;
  ls[tid] = v; __syncthreads();
#pragma unroll
  for (int off = 1; off < 256; off <<= 1) {
    int x = (tid >= off) ? ls[tid - off] : 0;
    __syncthreads(); ls[tid] += x; __syncthreads();
  }
  if (tid < SCAN_BLKS) bsum[tid] = ls[tid] - v;
}

// ep2 = {src | rel<<15 | t<<23, weight bits}  (t also implicit in segment;
// carried in spare bits so the gather can walk a node's full range).
// scan3 folded in: absolute position = base[key] + bsum[key>>10] + cursor++.
__global__ void fill_k(const int* __restrict__ src, const int* __restrict__ dst,
                       const int* __restrict__ etype, const int* __restrict__ etime,
                       const float* __restrict__ ew,
                       const int* __restrict__ base, const int* __restrict__ bsum,
                       int* __restrict__ cursor, uint2* __restrict__ ep2) {
  int i = blockIdx.x * blockDim.x + threadIdx.x;
  if (i >= N_EDGES) return;
  int t = etime[i];
  int key = dst[i] * T_STEPS + t;
  int pos = base[key] + bsum[key >> 10] + atomicAdd(&cursor[key], 1);
  uint2 e;
  e.x = (unsigned)src[i] | ((unsigned)etype[i] << 15) | ((unsigned)t << 23);
  e.y = __float_as_uint(ew[i]);
  ep2[pos] = e;
}

// ---- phase-A edge helpers: SCALAR metadata (wave-uniform), named accs ----
// Clamped index keeps all loads in-bounds (any ep2 slot is a real edge, so
// src<20000, rel<200 even for invalid slots); invalid edges get w=0 via a
// scalar cselect -> their contribution is +0 (bit-exact no-op).
#define EDGE_LOAD(jj, valid, M0, M1, TT)                                      \
  int TT; float M0, M1;                                                       \
  {                                                                           \
    int j_ = (jj) < (N_EDGES - 1) ? (jj) : (N_EDGES - 1);                     \
    uint2 e_ = ep2[j_];                                                       \
    unsigned x_ = (unsigned)__builtin_amdgcn_readfirstlane((int)e_.x);        \
    float w_ = __uint_as_float(                                               \
        (unsigned)__builtin_amdgcn_readfirstlane((int)e_.y));                 \
    w_ = (valid) ? w_ : 0.f;                                                  \
    int s_ = (int)(x_ & 0x7fffu), r_ = (int)((x_ >> 15) & 0xffu);             \
    TT = (int)((x_ >> 23) & 7u);                                              \
    float2 sv_ = *(const float2*)(nemb + (size_t)s_ * DIM + 2 * lane);        \
    float2 rv_ = *(const float2*)(remb + (size_t)r_ * DIM + 2 * lane);        \
    M0 = sv_.x * rv_.x * w_;                                                  \
    M1 = sv_.y * rv_.y * w_;                                                  \
  }

// scalar-branch accumulate: TT is wave-uniform (SGPR) -> compile-time-indexed
// named accumulators, 2 v_add per edge, decode on the scalar pipe.
#define ACC_SWITCH(TT, AXP, AYP, M0, M1)                                      \
  switch (TT) {                                                               \
    case 0: AXP##0 += M0; AYP##0 += M1; break;                                \
    case 1: AXP##1 += M0; AYP##1 += M1; break;                                \
    case 2: AXP##2 += M0; AYP##2 += M1; break;                                \
    case 3: AXP##3 += M0; AYP##3 += M1; break;                                \
    case 4: AXP##4 += M0; AYP##4 += M1; break;                                \
    case 5: AXP##5 += M0; AYP##5 += M1; break;                                \
    case 6: AXP##6 += M0; AYP##6 += M1; break;                                \
    default: AXP##7 += M0; AYP##7 += M1; break;                               \
  }

#define DECL8(P) float P##0 = 0.f, P##1 = 0.f, P##2 = 0.f, P##3 = 0.f,        \
                       P##4 = 0.f, P##5 = 0.f, P##6 = 0.f, P##7 = 0.f

#define STROW(TT, NL, AX, AY)                                                 \
  ((unsigned*)&aggL[((TT) * 16 + (NL)) * 136])[lane] = cvt_pk_bf16(AX, AY)

#define STROW8(NL, AXP, AYP)                                                  \
  STROW(0, NL, AXP##0, AYP##0); STROW(1, NL, AXP##1, AYP##1);                 \
  STROW(2, NL, AXP##2, AYP##2); STROW(3, NL, AXP##3, AYP##3);                 \
  STROW(4, NL, AXP##4, AYP##4); STROW(5, NL, AXP##5, AYP##5);                 \
  STROW(6, NL, AXP##6, AYP##6); STROW(7, NL, AXP##7, AYP##7)

// ---------------------------------------------------------------------------
// Fully-fused GATHER + encoder + GRU recurrence. One block per 16-node tile,
// 8 waves. Exact R15 (best measured: 192.06 total, fused 79.5, WRITE clean)
// with ONE register-neutral addition: phase C's t=0 step skips the S path
// via if(t>0) guards on the EXISTING inline-load form (no new arrays, no new
// accumulators -- R16's 4-chain split added ~16 live VGPRs and spilled +10MB
// scratch, the third spill of that signature: R9/R11/R16).
// t=0 skip is bit-exact: S==0, MFMA with A=0 adds +0; drops 8 MFMAs +
// 4 cvt_pk + 4 ds_writes + 4 ds_reads from step 0.
// Phase A (gather): wave-uniform scalar decode (R14) + 4 edges/node/iter
//   quad walk (R15): 8 meta chains + 16 row loads in flight; branchless
//   validity via scalar cselect (w=0). Spill tripwire: WRITE_SIZE == 10000.
// Phase B (encoder, hoisted): 32 MFMAs vs wenc -> hpk[t] packed bf16.
// Phase C (recurrence): per step t: H[t] (and S for t>0) -> double-buffered
//   LDS (stride 136), ONE barrier, inline per-ks A-frag loads, interleaved
//   accz/accc MFMA chains (R15 form), gates, update.
// MFMA 16x16x32_bf16 layouts (HW-verified): A: m=lane&15,k=quad*8+j;
// B: n=lane&15,k=quad*8+j;  C/D: col=lane&15, row=quad*4+reg.
// Double-buffer WAR safety: W(t) B(t) R(t) W(t+1)...: a wave at W(t+2)
// (overwrite of buffer t&1) passed B(t+1); every wave at B(t+1) completed
// R(t). Sb[1] first written t=1, first read t=1 after the barrier; Sb[0]
// first written t=2, read t=2 -> no uninitialized reads. aggL is written
// only in phase A (barrier-protected) and read-only afterwards.
// ---------------------------------------------------------------------------
__launch_bounds__(512, 4)
__global__ void fused_recur(const int* __restrict__ base,
                            const int* __restrict__ bsum,
                            const uint2* __restrict__ ep2,
                            const float* __restrict__ nemb,
                            const float* __restrict__ remb,
                            const unsigned short* __restrict__ pack,
                            const float* __restrict__ bz,
                            const float* __restrict__ bh,
                            float* __restrict__ out) {
  __shared__ unsigned short aggL[T_STEPS * 16 * 136];   // 34816 B
  __shared__ unsigned short Hb[2][16 * 136];            //  8704 B
  __shared__ unsigned short Sb[2][16 * 136];            //  8704 B
  int lane = threadIdx.x & 63;
  int nt = threadIdx.x >> 6;        // wave id: owns nodes {2nt,2nt+1} / col tile nt
  int q = lane >> 4, l15 = lane & 15;
  int tile = blockIdx.x;
  int row0 = tile * 16;
  int c = nt * 16 + l15;

  // ---- Phase A: scalar-decoded, branchless-validity, 8-chain quad walk ----
  {
    int kb0 = (row0 + nt * 2) * T_STEPS;
    int kb1 = kb0 + T_STEPS;
    int ke1 = kb1 + T_STEPS;
    int i0 = __builtin_amdgcn_readfirstlane(base[kb0] + bsum[kb0 >> 10]);
    int e0 = __builtin_amdgcn_readfirstlane(base[kb1] + bsum[kb1 >> 10]);
    int i1 = e0;                               // contiguous key ranges
    int e1 = __builtin_amdgcn_readfirstlane(base[ke1] + bsum[ke1 >> 10]);

    DECL8(ax0_); DECL8(ay0_); DECL8(ax1_); DECL8(ay1_);

    while (i0 < e0 || i1 < e1) {               // scalar control
      bool v00 = i0 < e0,     v01 = i0 + 1 < e0;
      bool v02 = i0 + 2 < e0, v03 = i0 + 3 < e0;
      bool v10 = i1 < e1,     v11 = i1 + 1 < e1;
      bool v12 = i1 + 2 < e1, v13 = i1 + 3 < e1;
      EDGE_LOAD(i0,     v00, m0a, m1a, ta);
      EDGE_LOAD(i0 + 1, v01, m0b, m1b, tb);
      EDGE_LOAD(i0 + 2, v02, m0c, m1c, tc);
      EDGE_LOAD(i0 + 3, v03, m0d, m1d, td);
      EDGE_LOAD(i1,     v10, m0e, m1e, te);
      EDGE_LOAD(i1 + 1, v11, m0f, m1f, tf);
      EDGE_LOAD(i1 + 2, v12, m0g, m1g, tg);
      EDGE_LOAD(i1 + 3, v13, m0h, m1h, th);
      ACC_SWITCH(ta, ax0_, ay0_, m0a, m1a);
      ACC_SWITCH(tb, ax0_, ay0_, m0b, m1b);
      ACC_SWITCH(tc, ax0_, ay0_, m0c, m1c);
      ACC_SWITCH(td, ax0_, ay0_, m0d, m1d);
      ACC_SWITCH(te, ax1_, ay1_, m0e, m1e);
      ACC_SWITCH(tf, ax1_, ay1_, m0f, m1f);
      ACC_SWITCH(tg, ax1_, ay1_, m0g, m1g);
      ACC_SWITCH(th, ax1_, ay1_, m0h, m1h);
      i0 = (i0 + 4 < e0) ? i0 + 4 : e0;
      i1 = (i1 + 4 < e1) ? i1 + 4 : e1;
    }

    int nl0 = nt * 2, nl1 = nt * 2 + 1;
    STROW8(nl0, ax0_, ay0_);
    STROW8(nl1, ax1_, ay1_);
  }
  __syncthreads();

  // ---- Phase B: encoder for ALL steps: H[t](:, nt-cols) as packed bf16 ----
  unsigned hpk[T_STEPS][2];
  {
    short8 wenc[4];
#pragma unroll
    for (int ks = 0; ks < 4; ks++)
      wenc[ks] = *(const short8*)(pack + ((nt * 4 + ks) * 64 + lane) * 8);
#pragma unroll
    for (int t = 0; t < T_STEPS; t++) {
      f32x4 acch = (f32x4){0.f, 0.f, 0.f, 0.f};
#pragma unroll
      for (int ks = 0; ks < 4; ks++) {
        short8 aA = *(const short8*)&aggL[(t * 16 + l15) * 136 + ks * 32 + q * 8];
        acch = __builtin_amdgcn_mfma_f32_16x16x32_bf16(aA, wenc[ks], acch, 0, 0, 0);
      }
      hpk[t][0] = cvt_pk_bf16(fast_tanh(acch[0]), fast_tanh(acch[1]));
      hpk[t][1] = cvt_pk_bf16(fast_tanh(acch[2]), fast_tanh(acch[3]));
    }
  }

  // recurrence weight B-fragments for this wave's nt
  short8 wz[4], uz[4], wh[4], uh[4];
#pragma unroll
  for (int ks = 0; ks < 4; ks++) {
    int fo = ((nt * 4 + ks) * 64 + lane) * 8;
    wz[ks] = *(const short8*)(pack + 16384 * 1 + fo);
    uz[ks] = *(const short8*)(pack + 16384 * 2 + fo);
    wh[ks] = *(const short8*)(pack + 16384 * 3 + fo);
    uh[ks] = *(const short8*)(pack + 16384 * 4 + fo);
  }
  float bzv = bz[c];
  float bhv = bh[c];

  f32x4 stC = (f32x4){0.f, 0.f, 0.f, 0.f};

  // ---- Phase C: GRU recurrence (R15 form + register-neutral t=0 S-skip) ----
#pragma unroll
  for (int t = 0; t < T_STEPS; t++) {
    unsigned short* hB = Hb[t & 1];
    unsigned short* sB = Sb[t & 1];
    hB[(q * 4 + 0) * 136 + c] = (unsigned short)hpk[t][0];
    hB[(q * 4 + 1) * 136 + c] = (unsigned short)(hpk[t][0] >> 16);
    hB[(q * 4 + 2) * 136 + c] = (unsigned short)hpk[t][1];
    hB[(q * 4 + 3) * 136 + c] = (unsigned short)(hpk[t][1] >> 16);
    if (t > 0) {
      unsigned s01 = cvt_pk_bf16(stC[0], stC[1]);
      unsigned s23 = cvt_pk_bf16(stC[2], stC[3]);
      sB[(q * 4 + 0) * 136 + c] = (unsigned short)s01;
      sB[(q * 4 + 1) * 136 + c] = (unsigned short)(s01 >> 16);
      sB[(q * 4 + 2) * 136 + c] = (unsigned short)s23;
      sB[(q * 4 + 3) * 136 + c] = (unsigned short)(s23 >> 16);
    }
    __syncthreads();

    f32x4 accz = (f32x4){bzv, bzv, bzv, bzv};
    f32x4 accc = (f32x4){bhv, bhv, bhv, bhv};
    if (t > 0) {
#pragma unroll
      for (int ks = 0; ks < 4; ks++) {
        short8 hA = *(const short8*)&hB[l15 * 136 + ks * 32 + q * 8];
        short8 sA = *(const short8*)&sB[l15 * 136 + ks * 32 + q * 8];
        accz = __builtin_amdgcn_mfma_f32_16x16x32_bf16(hA, wz[ks], accz, 0, 0, 0);
        accz = __builtin_amdgcn_mfma_f32_16x16x32_bf16(sA, uz[ks], accz, 0, 0, 0);
        accc = __builtin_amdgcn_mfma_f32_16x16x32_bf16(hA, wh[ks], accc, 0, 0, 0);
        accc = __builtin_amdgcn_mfma_f32_16x16x32_bf16(sA, uh[ks], accc, 0, 0, 0);
      }
    } else {
#pragma unroll
      for (int ks = 0; ks < 4; ks++) {
        short8 hA = *(const short8*)&hB[l15 * 136 + ks * 32 + q * 8];
        accz = __builtin_amdgcn_mfma_f32_16x16x32_bf16(hA, wz[ks], accz, 0, 0, 0);
        accc = __builtin_amdgcn_mfma_f32_16x16x32_bf16(hA, wh[ks], accc, 0, 0, 0);
      }
    }
#pragma unroll
    for (int r = 0; r < 4; r++) {
      float z = fast_sig(accz[r]);
      float cc = fast_tanh(accc[r]);
      stC[r] = (1.f - z) * stC[r] + z * cc;
    }
  }

  // final state -> out (fp32, C-layout positions)
#pragma unroll
  for (int r = 0; r < 4; r++)
    out[(size_t)(row0 + q * 4 + r) * DIM + c] = stC[r];
}

extern "C" void kernel_launch(void* const* d_in, const int* in_sizes, int n_in,
                              void* d_out, int out_size, void* d_ws, size_t ws_size,
                              hipStream_t stream) {
  const int* eidx  = (const int*)d_in[0];
  const int* src   = eidx;
  const int* dst   = eidx + N_EDGES;
  const int* etype = (const int*)d_in[1];
  const int* etime = (const int*)d_in[2];
  const float* ew   = (const float*)d_in[3];
  const float* nemb = (const float*)d_in[4];
  const float* remb = (const float*)d_in[5];
  const float* Wenc = (const float*)d_in[6];
  const float* Wz   = (const float*)d_in[7];
  const float* Uz   = (const float*)d_in[8];
  const float* Wh   = (const float*)d_in[9];
  const float* Uh   = (const float*)d_in[10];
  const float* bz   = (const float*)d_in[11];
  const float* bh   = (const float*)d_in[12];
  // d_in[13] = num_times (constant 8 for this problem's fixed shapes)

  // ws layout
  int* counts = (int*)d_ws;                                        // SCAN_N
  int* cursor = counts + SCAN_N;                                   // KEYS
  int* bsum   = cursor + KEYS;                                     // 256
  int* base   = bsum + 256;                                        // SCAN_N
  uint2* ep2  = (uint2*)(base + ((SCAN_N + 1) & ~1));              // E, 8B-aligned
  unsigned short* pack = (unsigned short*)(ep2 + N_EDGES);         // 5*16384
  float* outp = (float*)d_out;

  hipMemsetAsync(counts, 0, (size_t)(SCAN_N + KEYS) * sizeof(int), stream);
  repack5<<<(5 * 16384 + 255) / 256, 256, 0, stream>>>(Wenc, Wz, Uz, Wh, Uh, pack);
  hist_k<<<(N_EDGES + 255) / 256, 256, 0, stream>>>(dst, etime, counts);
  scan1_k<<<SCAN_BLKS, 256, 0, stream>>>(counts, base, bsum);
  scan2_k<<<1, 256, 0, stream>>>(bsum);
  fill_k<<<(N_EDGES + 255) / 256, 256, 0, stream>>>(src, dst, etype, etime, ew,
                                                    base, bsum, cursor, ep2);
  fused_recur<<<N_TILES, 512, 0, stream>>>(base, bsum, ep2, nemb, remb,
                                           pack, bz, bh, outp);
}

// Round 18
// 190.761 us; speedup vs baseline: 1.0106x; 1.0022x over previous
//
#include <hip/hip_runtime.h>

#define N_NODES 20000
#define N_REL 200
#define N_EDGES 200000
#define DIM 128
#define T_STEPS 8
#define N_TILES (N_NODES / 16)              // 1250
#define KEYS (N_NODES * T_STEPS)            // 160000 (dst,t) segments
#define SCAN_N (KEYS + 1)                   // 160001
#define SCAN_BLKS ((SCAN_N + 1023) / 1024)  // 157

typedef short short8 __attribute__((ext_vector_type(8)));
typedef float f32x4 __attribute__((ext_vector_type(4)));

static __device__ __forceinline__ unsigned short f2bf(float f) {
  union { float f; unsigned u; } v; v.f = f;
  unsigned r = v.u + 0x7fffu + ((v.u >> 16) & 1u);   // RNE
  return (unsigned short)(r >> 16);
}
// packed f32x2 -> bf16x2 (RNE), 1 instruction
static __device__ __forceinline__ unsigned cvt_pk_bf16(float lo, float hi) {
  unsigned r;
  asm("v_cvt_pk_bf16_f32 %0, %1, %2" : "=v"(r) : "v"(lo), "v"(hi));
  return r;
}
static __device__ __forceinline__ float fast_tanh(float x) {
  float e = __expf(2.f * x);           // inf-safe: x>>0 -> 1, x<<0 -> -1
  return 1.f - 2.f / (e + 1.f);
}
static __device__ __forceinline__ float fast_sig(float x) {
  return 1.f / (1.f + __expf(-x));
}

// ---------------------------------------------------------------------------
// Repack the five 128x128 fp32 weight matrices (row-major W[k][n]) into bf16
// MFMA B-fragment order: pack[m][((nt*4+ks)*64+lane)*8+j] = bf16(W[k][n]),
// n = nt*16 + (lane&15), k = ks*32 + (lane>>4)*8 + j.
// Slots: 0=Wenc 1=Wz 2=Uz 3=Wh 4=Uh.
// ---------------------------------------------------------------------------
__global__ void repack5(const float* __restrict__ w0,
                        const float* __restrict__ w1,
                        const float* __restrict__ w2,
                        const float* __restrict__ w3,
                        const float* __restrict__ w4,
                        unsigned short* __restrict__ pack) {
  int i = blockIdx.x * blockDim.x + threadIdx.x;
  if (i >= 5 * 16384) return;
  int m = i >> 14, r = i & 16383;
  int j = r & 7, lane = (r >> 3) & 63, ks = (r >> 9) & 3, nt = (r >> 11) & 7;
  int n = nt * 16 + (lane & 15);
  int k = ks * 32 + (lane >> 4) * 8 + j;
  const float* w = (m == 0) ? w0 : (m == 1) ? w1 : (m == 2) ? w2
                 : (m == 3) ? w3 : w4;
  pack[i] = f2bf(w[k * DIM + n]);
}

// ----------------- CSR build: bucket by key = dst*8 + t --------------------
__global__ void hist_k(const int* __restrict__ dst, const int* __restrict__ etime,
                       int* __restrict__ counts) {
  int i = blockIdx.x * blockDim.x + threadIdx.x;
  if (i >= N_EDGES) return;
  atomicAdd(&counts[dst[i] * T_STEPS + etime[i]], 1);
}

__global__ void scan1_k(const int* __restrict__ counts,
                        int* __restrict__ base, int* __restrict__ bsum) {
  __shared__ int ls[256];
  int tid = threadIdx.x;
  int i0 = blockIdx.x * 1024 + tid * 4;
  int v[4], ts = 0;
#pragma unroll
  for (int r = 0; r < 4; r++) {
    v[r] = (i0 + r < SCAN_N) ? counts[i0 + r] : 0;
    ts += v[r];
  }
  ls[tid] = ts; __syncthreads();
#pragma unroll
  for (int off = 1; off < 256; off <<= 1) {
    int x = (tid >= off) ? ls[tid - off] : 0;
    __syncthreads(); ls[tid] += x; __syncthreads();
  }
  int run = ls[tid] - ts;
  if (tid == 255) bsum[blockIdx.x] = ls[255];
#pragma unroll
  for (int r = 0; r < 4; r++) {
    if (i0 + r < SCAN_N) base[i0 + r] = run;
    run += v[r];
  }
}

__global__ void scan2_k(int* __restrict__ bsum) {
  __shared__ int ls[256];
  int tid = threadIdx.x;
  int v = (tid < SCAN_BLKS) ? bsum[tid] : 0;
  ls[tid] = v; __syncthreads();
#pragma unroll
  for (int off = 1; off < 256; off <<= 1) {
    int x = (tid >= off) ? ls[tid - off] : 0;
    __syncthreads(); ls[tid] += x; __syncthreads();
  }
  if (tid < SCAN_BLKS) bsum[tid] = ls[tid] - v;
}

// ep2 = {src | rel<<15 | t<<23, weight bits}  (t also implicit in segment;
// carried in spare bits so the gather can walk a node's full range).
// scan3 folded in: absolute position = base[key] + bsum[key>>10] + cursor++.
__global__ void fill_k(const int* __restrict__ src, const int* __restrict__ dst,
                       const int* __restrict__ etype, const int* __restrict__ etime,
                       const float* __restrict__ ew,
                       const int* __restrict__ base, const int* __restrict__ bsum,
                       int* __restrict__ cursor, uint2* __restrict__ ep2) {
  int i = blockIdx.x * blockDim.x + threadIdx.x;
  if (i >= N_EDGES) return;
  int t = etime[i];
  int key = dst[i] * T_STEPS + t;
  int pos = base[key] + bsum[key >> 10] + atomicAdd(&cursor[key], 1);
  uint2 e;
  e.x = (unsigned)src[i] | ((unsigned)etype[i] << 15) | ((unsigned)t << 23);
  e.y = __float_as_uint(ew[i]);
  ep2[pos] = e;
}

// ---- phase-A edge helpers: SCALAR metadata (wave-uniform), named accs ----
// Clamped index keeps all loads in-bounds (any ep2 slot is a real edge, so
// src<20000, rel<200 even for invalid slots); invalid edges get w=0 via a
// scalar cselect -> their contribution is +0 (bit-exact no-op).
#define EDGE_LOAD(jj, valid, M0, M1, TT)                                      \
  int TT; float M0, M1;                                                       \
  {                                                                           \
    int j_ = (jj) < (N_EDGES - 1) ? (jj) : (N_EDGES - 1);                     \
    uint2 e_ = ep2[j_];                                                       \
    unsigned x_ = (unsigned)__builtin_amdgcn_readfirstlane((int)e_.x);        \
    float w_ = __uint_as_float(                                               \
        (unsigned)__builtin_amdgcn_readfirstlane((int)e_.y));                 \
    w_ = (valid) ? w_ : 0.f;                                                  \
    int s_ = (int)(x_ & 0x7fffu), r_ = (int)((x_ >> 15) & 0xffu);             \
    TT = (int)((x_ >> 23) & 7u);                                              \
    float2 sv_ = *(const float2*)(nemb + (size_t)s_ * DIM + 2 * lane);        \
    float2 rv_ = *(const float2*)(remb + (size_t)r_ * DIM + 2 * lane);        \
    M0 = sv_.x * rv_.x * w_;                                                  \
    M1 = sv_.y * rv_.y * w_;                                                  \
  }

// scalar-branch accumulate: TT is wave-uniform (SGPR) -> compile-time-indexed
// named accumulators, 2 v_add per edge, decode on the scalar pipe.
#define ACC_SWITCH(TT, AXP, AYP, M0, M1)                                      \
  switch (TT) {                                                               \
    case 0: AXP##0 += M0; AYP##0 += M1; break;                                \
    case 1: AXP##1 += M0; AYP##1 += M1; break;                                \
    case 2: AXP##2 += M0; AYP##2 += M1; break;                                \
    case 3: AXP##3 += M0; AYP##3 += M1; break;                                \
    case 4: AXP##4 += M0; AYP##4 += M1; break;                                \
    case 5: AXP##5 += M0; AYP##5 += M1; break;                                \
    case 6: AXP##6 += M0; AYP##6 += M1; break;                                \
    default: AXP##7 += M0; AYP##7 += M1; break;                               \
  }

#define DECL8(P) float P##0 = 0.f, P##1 = 0.f, P##2 = 0.f, P##3 = 0.f,        \
                       P##4 = 0.f, P##5 = 0.f, P##6 = 0.f, P##7 = 0.f

#define STROW(TT, NL, AX, AY)                                                 \
  ((unsigned*)&aggL[((TT) * 16 + (NL)) * 136])[lane] = cvt_pk_bf16(AX, AY)

#define STROW8(NL, AXP, AYP)                                                  \
  STROW(0, NL, AXP##0, AYP##0); STROW(1, NL, AXP##1, AYP##1);                 \
  STROW(2, NL, AXP##2, AYP##2); STROW(3, NL, AXP##3, AYP##3);                 \
  STROW(4, NL, AXP##4, AYP##4); STROW(5, NL, AXP##5, AYP##5);                 \
  STROW(6, NL, AXP##6, AYP##6); STROW(7, NL, AXP##7, AYP##7)

// ---------------------------------------------------------------------------
// Fully-fused GATHER + encoder + GRU recurrence. One block per 16-node tile,
// 8 waves. R17 base (best: 191.2 total, fused 77.8) with ONE change:
// Hb is ELIMINATED. After phase B all 8 H[t] tiles are bulk-written into
// aggL (agg values are dead once phase B's reads finish -- fenced by two
// barriers). Phase C's per-step body shrinks to the S-exchange only:
// 4 ds_writes + 1 barrier + 8 ds_reads + 16 MFMAs; H[t] A-frags come from
// the now read-only aggL (no hazard). Unlike R10's failed hoist, the MFMAs
// STAY in the loop (no zh/ch[8] register block), and hpk's 16 VGPRs die at
// the bulk write -> phase-C register pressure DROPS. t=0 touches no S and
// needs no barrier (H reads fenced by the bulk-write barrier).
// LDS 52224 -> 43520 B. Arithmetic bit-identical (same bf16 H values via
// LDS, same gate order) -> absmax must stay exactly 0.00831604.
// Phase A (gather): wave-uniform scalar decode (R14) + 4 edges/node/iter
//   quad walk (R15); branchless validity via scalar cselect (w=0).
//   Spill tripwire: WRITE_SIZE == 10000 KB.
// Phase B (encoder, hoisted): 32 MFMAs vs wenc -> hpk[t] packed bf16.
// MFMA 16x16x32_bf16 layouts (HW-verified): A: m=lane&15,k=quad*8+j;
// B: n=lane&15,k=quad*8+j;  C/D: col=lane&15, row=quad*4+reg.
// Sb double-buffer WAR: W(t) B(t) R(t) W(t+1)...: a wave at W(t+2)
// (overwrite of buffer t&1) passed B(t+1); every wave at B(t+1) completed
// R(t). Sb[1] first written t=1, first read t=1 after the barrier; Sb[0]
// first written t=2, read t=2 -> no uninitialized reads. aggL: agg reads
// (phase B) fenced from H writes by a barrier; H writes fenced from phase-C
// reads by a barrier; aggL is read-only during phase C.
// ---------------------------------------------------------------------------
__launch_bounds__(512, 4)
__global__ void fused_recur(const int* __restrict__ base,
                            const int* __restrict__ bsum,
                            const uint2* __restrict__ ep2,
                            const float* __restrict__ nemb,
                            const float* __restrict__ remb,
                            const unsigned short* __restrict__ pack,
                            const float* __restrict__ bz,
                            const float* __restrict__ bh,
                            float* __restrict__ out) {
  __shared__ unsigned short aggL[T_STEPS * 16 * 136];   // 34816 B (agg, then H)
  __shared__ unsigned short Sb[2][16 * 136];            //  8704 B
  int lane = threadIdx.x & 63;
  int nt = threadIdx.x >> 6;        // wave id: owns nodes {2nt,2nt+1} / col tile nt
  int q = lane >> 4, l15 = lane & 15;
  int tile = blockIdx.x;
  int row0 = tile * 16;
  int c = nt * 16 + l15;

  // ---- Phase A: scalar-decoded, branchless-validity, 8-chain quad walk ----
  {
    int kb0 = (row0 + nt * 2) * T_STEPS;
    int kb1 = kb0 + T_STEPS;
    int ke1 = kb1 + T_STEPS;
    int i0 = __builtin_amdgcn_readfirstlane(base[kb0] + bsum[kb0 >> 10]);
    int e0 = __builtin_amdgcn_readfirstlane(base[kb1] + bsum[kb1 >> 10]);
    int i1 = e0;                               // contiguous key ranges
    int e1 = __builtin_amdgcn_readfirstlane(base[ke1] + bsum[ke1 >> 10]);

    DECL8(ax0_); DECL8(ay0_); DECL8(ax1_); DECL8(ay1_);

    while (i0 < e0 || i1 < e1) {               // scalar control
      bool v00 = i0 < e0,     v01 = i0 + 1 < e0;
      bool v02 = i0 + 2 < e0, v03 = i0 + 3 < e0;
      bool v10 = i1 < e1,     v11 = i1 + 1 < e1;
      bool v12 = i1 + 2 < e1, v13 = i1 + 3 < e1;
      EDGE_LOAD(i0,     v00, m0a, m1a, ta);
      EDGE_LOAD(i0 + 1, v01, m0b, m1b, tb);
      EDGE_LOAD(i0 + 2, v02, m0c, m1c, tc);
      EDGE_LOAD(i0 + 3, v03, m0d, m1d, td);
      EDGE_LOAD(i1,     v10, m0e, m1e, te);
      EDGE_LOAD(i1 + 1, v11, m0f, m1f, tf);
      EDGE_LOAD(i1 + 2, v12, m0g, m1g, tg);
      EDGE_LOAD(i1 + 3, v13, m0h, m1h, th);
      ACC_SWITCH(ta, ax0_, ay0_, m0a, m1a);
      ACC_SWITCH(tb, ax0_, ay0_, m0b, m1b);
      ACC_SWITCH(tc, ax0_, ay0_, m0c, m1c);
      ACC_SWITCH(td, ax0_, ay0_, m0d, m1d);
      ACC_SWITCH(te, ax1_, ay1_, m0e, m1e);
      ACC_SWITCH(tf, ax1_, ay1_, m0f, m1f);
      ACC_SWITCH(tg, ax1_, ay1_, m0g, m1g);
      ACC_SWITCH(th, ax1_, ay1_, m0h, m1h);
      i0 = (i0 + 4 < e0) ? i0 + 4 : e0;
      i1 = (i1 + 4 < e1) ? i1 + 4 : e1;
    }

    int nl0 = nt * 2, nl1 = nt * 2 + 1;
    STROW8(nl0, ax0_, ay0_);
    STROW8(nl1, ax1_, ay1_);
  }
  __syncthreads();

  // ---- Phase B: encoder for ALL steps: H[t](:, nt-cols) as packed bf16 ----
  unsigned hpk[T_STEPS][2];
  {
    short8 wenc[4];
#pragma unroll
    for (int ks = 0; ks < 4; ks++)
      wenc[ks] = *(const short8*)(pack + ((nt * 4 + ks) * 64 + lane) * 8);
#pragma unroll
    for (int t = 0; t < T_STEPS; t++) {
      f32x4 acch = (f32x4){0.f, 0.f, 0.f, 0.f};
#pragma unroll
      for (int ks = 0; ks < 4; ks++) {
        short8 aA = *(const short8*)&aggL[(t * 16 + l15) * 136 + ks * 32 + q * 8];
        acch = __builtin_amdgcn_mfma_f32_16x16x32_bf16(aA, wenc[ks], acch, 0, 0, 0);
      }
      hpk[t][0] = cvt_pk_bf16(fast_tanh(acch[0]), fast_tanh(acch[1]));
      hpk[t][1] = cvt_pk_bf16(fast_tanh(acch[2]), fast_tanh(acch[3]));
    }
  }
  __syncthreads();   // all aggL (agg) reads complete before H overwrite

  // ---- bulk write: all 8 H[t] -> aggL (agg is dead); hpk dies here ----
#pragma unroll
  for (int t = 0; t < T_STEPS; t++) {
    int rbase = (t * 16 + q * 4) * 136 + c;
    aggL[rbase + 0 * 136] = (unsigned short)hpk[t][0];
    aggL[rbase + 1 * 136] = (unsigned short)(hpk[t][0] >> 16);
    aggL[rbase + 2 * 136] = (unsigned short)hpk[t][1];
    aggL[rbase + 3 * 136] = (unsigned short)(hpk[t][1] >> 16);
  }

  // recurrence weight B-fragments for this wave's nt
  short8 wz[4], uz[4], wh[4], uh[4];
#pragma unroll
  for (int ks = 0; ks < 4; ks++) {
    int fo = ((nt * 4 + ks) * 64 + lane) * 8;
    wz[ks] = *(const short8*)(pack + 16384 * 1 + fo);
    uz[ks] = *(const short8*)(pack + 16384 * 2 + fo);
    wh[ks] = *(const short8*)(pack + 16384 * 3 + fo);
    uh[ks] = *(const short8*)(pack + 16384 * 4 + fo);
  }
  float bzv = bz[c];
  float bhv = bh[c];

  __syncthreads();   // H visible to all waves; aggL read-only from here

  // ---- Phase C: t=0 (S==0 -> H-only, no barrier, no Sb access) ----
  f32x4 stC;
  {
    f32x4 accz = (f32x4){bzv, bzv, bzv, bzv};
    f32x4 accc = (f32x4){bhv, bhv, bhv, bhv};
#pragma unroll
    for (int ks = 0; ks < 4; ks++) {
      short8 hA = *(const short8*)&aggL[(0 * 16 + l15) * 136 + ks * 32 + q * 8];
      accz = __builtin_amdgcn_mfma_f32_16x16x32_bf16(hA, wz[ks], accz, 0, 0, 0);
      accc = __builtin_amdgcn_mfma_f32_16x16x32_bf16(hA, wh[ks], accc, 0, 0, 0);
    }
#pragma unroll
    for (int r = 0; r < 4; r++) {
      float z = fast_sig(accz[r]);
      float cc = fast_tanh(accc[r]);
      stC[r] = z * cc;                  // S0 = (1-z)*0 + z*c
    }
  }

  // ---- Phase C: t=1..7 (S-exchange only; H from read-only aggL) ----
#pragma unroll
  for (int t = 1; t < T_STEPS; t++) {
    unsigned short* sB = Sb[t & 1];
    unsigned s01 = cvt_pk_bf16(stC[0], stC[1]);
    unsigned s23 = cvt_pk_bf16(stC[2], stC[3]);
    sB[(q * 4 + 0) * 136 + c] = (unsigned short)s01;
    sB[(q * 4 + 1) * 136 + c] = (unsigned short)(s01 >> 16);
    sB[(q * 4 + 2) * 136 + c] = (unsigned short)s23;
    sB[(q * 4 + 3) * 136 + c] = (unsigned short)(s23 >> 16);
    __syncthreads();

    f32x4 accz = (f32x4){bzv, bzv, bzv, bzv};
    f32x4 accc = (f32x4){bhv, bhv, bhv, bhv};
#pragma unroll
    for (int ks = 0; ks < 4; ks++) {
      short8 hA = *(const short8*)&aggL[(t * 16 + l15) * 136 + ks * 32 + q * 8];
      short8 sA = *(const short8*)&sB[l15 * 136 + ks * 32 + q * 8];
      accz = __builtin_amdgcn_mfma_f32_16x16x32_bf16(hA, wz[ks], accz, 0, 0, 0);
      accz = __builtin_amdgcn_mfma_f32_16x16x32_bf16(sA, uz[ks], accz, 0, 0, 0);
      accc = __builtin_amdgcn_mfma_f32_16x16x32_bf16(hA, wh[ks], accc, 0, 0, 0);
      accc = __builtin_amdgcn_mfma_f32_16x16x32_bf16(sA, uh[ks], accc, 0, 0, 0);
    }
#pragma unroll
    for (int r = 0; r < 4; r++) {
      float z = fast_sig(accz[r]);
      float cc = fast_tanh(accc[r]);
      stC[r] = (1.f - z) * stC[r] + z * cc;
    }
  }

  // final state -> out (fp32, C-layout positions)
#pragma unroll
  for (int r = 0; r < 4; r++)
    out[(size_t)(row0 + q * 4 + r) * DIM + c] = stC[r];
}

extern "C" void kernel_launch(void* const* d_in, const int* in_sizes, int n_in,
                              void* d_out, int out_size, void* d_ws, size_t ws_size,
                              hipStream_t stream) {
  const int* eidx  = (const int*)d_in[0];
  const int* src   = eidx;
  const int* dst   = eidx + N_EDGES;
  const int* etype = (const int*)d_in[1];
  const int* etime = (const int*)d_in[2];
  const float* ew   = (const float*)d_in[3];
  const float* nemb = (const float*)d_in[4];
  const float* remb = (const float*)d_in[5];
  const float* Wenc = (const float*)d_in[6];
  const float* Wz   = (const float*)d_in[7];
  const float* Uz   = (const float*)d_in[8];
  const float* Wh   = (const float*)d_in[9];
  const float* Uh   = (const float*)d_in[10];
  const float* bz   = (const float*)d_in[11];
  const float* bh   = (const float*)d_in[12];
  // d_in[13] = num_times (constant 8 for this problem's fixed shapes)

  // ws layout
  int* counts = (int*)d_ws;                                        // SCAN_N
  int* cursor = counts + SCAN_N;                                   // KEYS
  int* bsum   = cursor + KEYS;                                     // 256
  int* base   = bsum + 256;                                        // SCAN_N
  uint2* ep2  = (uint2*)(base + ((SCAN_N + 1) & ~1));              // E, 8B-aligned
  unsigned short* pack = (unsigned short*)(ep2 + N_EDGES);         // 5*16384
  float* outp = (float*)d_out;

  hipMemsetAsync(counts, 0, (size_t)(SCAN_N + KEYS) * sizeof(int), stream);
  repack5<<<(5 * 16384 + 255) / 256, 256, 0, stream>>>(Wenc, Wz, Uz, Wh, Uh, pack);
  hist_k<<<(N_EDGES + 255) / 256, 256, 0, stream>>>(dst, etime, counts);
  scan1_k<<<SCAN_BLKS, 256, 0, stream>>>(counts, base, bsum);
  scan2_k<<<1, 256, 0, stream>>>(bsum);
  fill_k<<<(N_EDGES + 255) / 256, 256, 0, stream>>>(src, dst, etype, etime, ew,
                                                    base, bsum, cursor, ep2);
  fused_recur<<<N_TILES, 512, 0, stream>>>(base, bsum, ep2, nemb, remb,
                                           pack, bz, bh, outp);
}

// Round 19
// 185.186 us; speedup vs baseline: 1.0411x; 1.0301x over previous
//
#include <hip/hip_runtime.h>

#define N_NODES 20000
#define N_REL 200
#define N_EDGES 200000
#define DIM 128
#define T_STEPS 8
#define N_TILES (N_NODES / 16)              // 1250
#define KEYS (N_NODES * T_STEPS)            // 160000 (dst,t) segments
#define SCAN_N (KEYS + 1)                   // 160001
#define SCAN_BLKS ((SCAN_N + 1023) / 1024)  // 157
#define ZERO_N (SCAN_N + KEYS)              // 320001 ints (counts + cursor)

typedef short short8 __attribute__((ext_vector_type(8)));
typedef float f32x4 __attribute__((ext_vector_type(4)));

static __device__ __forceinline__ unsigned short f2bf(float f) {
  union { float f; unsigned u; } v; v.f = f;
  unsigned r = v.u + 0x7fffu + ((v.u >> 16) & 1u);   // RNE
  return (unsigned short)(r >> 16);
}
// packed f32x2 -> bf16x2 (RNE), 1 instruction
static __device__ __forceinline__ unsigned cvt_pk_bf16(float lo, float hi) {
  unsigned r;
  asm("v_cvt_pk_bf16_f32 %0, %1, %2" : "=v"(r) : "v"(lo), "v"(hi));
  return r;
}
static __device__ __forceinline__ float fast_tanh(float x) {
  float e = __expf(2.f * x);           // inf-safe: x>>0 -> 1, x<<0 -> -1
  return 1.f - 2.f / (e + 1.f);
}
static __device__ __forceinline__ float fast_sig(float x) {
  return 1.f / (1.f + __expf(-x));
}

// ---------------------------------------------------------------------------
// Repack the five 128x128 fp32 weight matrices (row-major W[k][n]) into bf16
// MFMA B-fragment order: pack[m][((nt*4+ks)*64+lane)*8+j] = bf16(W[k][n]),
// n = nt*16 + (lane&15), k = ks*32 + (lane>>4)*8 + j.
// Slots: 0=Wenc 1=Wz 2=Uz 3=Wh 4=Uh.
// Also zeroes counts+cursor (320001 ints; 81920 threads x 4 = 327680 slots)
// -- replaces the hipMemsetAsync dispatch (runs before hist_k/fill_k).
// ---------------------------------------------------------------------------
__global__ void repack5(const float* __restrict__ w0,
                        const float* __restrict__ w1,
                        const float* __restrict__ w2,
                        const float* __restrict__ w3,
                        const float* __restrict__ w4,
                        unsigned short* __restrict__ pack,
                        int* __restrict__ zero_base) {
  int i = blockIdx.x * blockDim.x + threadIdx.x;
  int z0 = i * 4;
#pragma unroll
  for (int r = 0; r < 4; r++)
    if (z0 + r < ZERO_N) zero_base[z0 + r] = 0;
  if (i >= 5 * 16384) return;
  int m = i >> 14, r = i & 16383;
  int j = r & 7, lane = (r >> 3) & 63, ks = (r >> 9) & 3, nt = (r >> 11) & 7;
  int n = nt * 16 + (lane & 15);
  int k = ks * 32 + (lane >> 4) * 8 + j;
  const float* w = (m == 0) ? w0 : (m == 1) ? w1 : (m == 2) ? w2
                 : (m == 3) ? w3 : w4;
  pack[i] = f2bf(w[k * DIM + n]);
}

// ----------------- CSR build: bucket by key = dst*8 + t --------------------
__global__ void hist_k(const int* __restrict__ dst, const int* __restrict__ etime,
                       int* __restrict__ counts) {
  int i = blockIdx.x * blockDim.x + threadIdx.x;
  if (i >= N_EDGES) return;
  atomicAdd(&counts[dst[i] * T_STEPS + etime[i]], 1);
}

__global__ void scan1_k(const int* __restrict__ counts,
                        int* __restrict__ base, int* __restrict__ bsum) {
  __shared__ int ls[256];
  int tid = threadIdx.x;
  int i0 = blockIdx.x * 1024 + tid * 4;
  int v[4], ts = 0;
#pragma unroll
  for (int r = 0; r < 4; r++) {
    v[r] = (i0 + r < SCAN_N) ? counts[i0 + r] : 0;
    ts += v[r];
  }
  ls[tid] = ts; __syncthreads();
#pragma unroll
  for (int off = 1; off < 256; off <<= 1) {
    int x = (tid >= off) ? ls[tid - off] : 0;
    __syncthreads(); ls[tid] += x; __syncthreads();
  }
  int run = ls[tid] - ts;
  if (tid == 255) bsum[blockIdx.x] = ls[255];
#pragma unroll
  for (int r = 0; r < 4; r++) {
    if (i0 + r < SCAN_N) base[i0 + r] = run;
    run += v[r];
  }
}

__global__ void scan2_k(int* __restrict__ bsum) {
  __shared__ int ls[256];
  int tid = threadIdx.x;
  int v = (tid < SCAN_BLKS) ? bsum[tid] : 0;
  ls[tid] = v; __syncthreads();
#pragma unroll
  for (int off = 1; off < 256; off <<= 1) {
    int x = (tid >= off) ? ls[tid - off] : 0;
    __syncthreads(); ls[tid] += x; __syncthreads();
  }
  if (tid < SCAN_BLKS) bsum[tid] = ls[tid] - v;
}

// ep2 = {src | rel<<15 | t<<23, weight bits}  (t also implicit in segment;
// carried in spare bits so the gather can walk a node's full range).
// scan3 folded in: absolute position = base[key] + bsum[key>>10] + cursor++.
__global__ void fill_k(const int* __restrict__ src, const int* __restrict__ dst,
                       const int* __restrict__ etype, const int* __restrict__ etime,
                       const float* __restrict__ ew,
                       const int* __restrict__ base, const int* __restrict__ bsum,
                       int* __restrict__ cursor, uint2* __restrict__ ep2) {
  int i = blockIdx.x * blockDim.x + threadIdx.x;
  if (i >= N_EDGES) return;
  int t = etime[i];
  int key = dst[i] * T_STEPS + t;
  int pos = base[key] + bsum[key >> 10] + atomicAdd(&cursor[key], 1);
  uint2 e;
  e.x = (unsigned)src[i] | ((unsigned)etype[i] << 15) | ((unsigned)t << 23);
  e.y = __float_as_uint(ew[i]);
  ep2[pos] = e;
}

// ---- phase-A edge helpers: SCALAR metadata (wave-uniform), named accs ----
// Clamped index keeps all loads in-bounds (any ep2 slot is a real edge, so
// src<20000, rel<200 even for invalid slots); invalid edges get w=0 via a
// scalar cselect -> their contribution is +0 (bit-exact no-op).
#define EDGE_LOAD(jj, valid, M0, M1, TT)                                      \
  int TT; float M0, M1;                                                       \
  {                                                                           \
    int j_ = (jj) < (N_EDGES - 1) ? (jj) : (N_EDGES - 1);                     \
    uint2 e_ = ep2[j_];                                                       \
    unsigned x_ = (unsigned)__builtin_amdgcn_readfirstlane((int)e_.x);        \
    float w_ = __uint_as_float(                                               \
        (unsigned)__builtin_amdgcn_readfirstlane((int)e_.y));                 \
    w_ = (valid) ? w_ : 0.f;                                                  \
    int s_ = (int)(x_ & 0x7fffu), r_ = (int)((x_ >> 15) & 0xffu);             \
    TT = (int)((x_ >> 23) & 7u);                                              \
    float2 sv_ = *(const float2*)(nemb + (size_t)s_ * DIM + 2 * lane);        \
    float2 rv_ = *(const float2*)(remb + (size_t)r_ * DIM + 2 * lane);        \
    M0 = sv_.x * rv_.x * w_;                                                  \
    M1 = sv_.y * rv_.y * w_;                                                  \
  }

// scalar-branch accumulate: TT is wave-uniform (SGPR) -> compile-time-indexed
// named accumulators, 2 v_add per edge, decode on the scalar pipe.
#define ACC_SWITCH(TT, AXP, AYP, M0, M1)                                      \
  switch (TT) {                                                               \
    case 0: AXP##0 += M0; AYP##0 += M1; break;                                \
    case 1: AXP##1 += M0; AYP##1 += M1; break;                                \
    case 2: AXP##2 += M0; AYP##2 += M1; break;                                \
    case 3: AXP##3 += M0; AYP##3 += M1; break;                                \
    case 4: AXP##4 += M0; AYP##4 += M1; break;                                \
    case 5: AXP##5 += M0; AYP##5 += M1; break;                                \
    case 6: AXP##6 += M0; AYP##6 += M1; break;                                \
    default: AXP##7 += M0; AYP##7 += M1; break;                               \
  }

#define DECL8(P) float P##0 = 0.f, P##1 = 0.f, P##2 = 0.f, P##3 = 0.f,        \
                       P##4 = 0.f, P##5 = 0.f, P##6 = 0.f, P##7 = 0.f

#define STROW(TT, NL, AX, AY)                                                 \
  ((unsigned*)&aggL[((TT) * 16 + (NL)) * 136])[lane] = cvt_pk_bf16(AX, AY)

#define STROW8(NL, AXP, AYP)                                                  \
  STROW(0, NL, AXP##0, AYP##0); STROW(1, NL, AXP##1, AYP##1);                 \
  STROW(2, NL, AXP##2, AYP##2); STROW(3, NL, AXP##3, AYP##3);                 \
  STROW(4, NL, AXP##4, AYP##4); STROW(5, NL, AXP##5, AYP##5);                 \
  STROW(6, NL, AXP##6, AYP##6); STROW(7, NL, AXP##7, AYP##7)

// ---------------------------------------------------------------------------
// Fully-fused GATHER + encoder + GRU recurrence. One block per 16-node tile,
// 8 waves. EXACT R17 kernel (best measured fused: 77.8 us, WRITE clean) --
// R18's Hb-elimination regressed fused ~4 us (serialized H bulk-store +
// extra barrier), so R17's Hb-form is restored.
// Phase A (gather): wave-uniform scalar decode (R14) + 4 edges/node/iter
//   quad walk (R15); branchless validity via scalar cselect (w=0).
//   Spill tripwire: WRITE_SIZE == 10000 KB.
// Phase B (encoder, hoisted): 32 MFMAs vs wenc -> hpk[t] packed bf16.
// Phase C (recurrence): per step t: H[t] (and S for t>0) -> double-buffered
//   LDS (stride 136), ONE barrier, inline per-ks A-frag loads, interleaved
//   accz/accc MFMA chains; register-neutral t=0 S-skip via if(t>0) guards
//   (bit-exact: S==0, MFMA with A=0 adds +0).
// MFMA 16x16x32_bf16 layouts (HW-verified): A: m=lane&15,k=quad*8+j;
// B: n=lane&15,k=quad*8+j;  C/D: col=lane&15, row=quad*4+reg.
// Double-buffer WAR safety: W(t) B(t) R(t) W(t+1)...: a wave at W(t+2)
// (overwrite of buffer t&1) passed B(t+1); every wave at B(t+1) completed
// R(t). Sb[1] first written t=1, first read t=1 after the barrier; Sb[0]
// first written t=2, read t=2 -> no uninitialized reads. aggL is written
// only in phase A (barrier-protected) and read-only afterwards.
// ---------------------------------------------------------------------------
__launch_bounds__(512, 4)
__global__ void fused_recur(const int* __restrict__ base,
                            const int* __restrict__ bsum,
                            const uint2* __restrict__ ep2,
                            const float* __restrict__ nemb,
                            const float* __restrict__ remb,
                            const unsigned short* __restrict__ pack,
                            const float* __restrict__ bz,
                            const float* __restrict__ bh,
                            float* __restrict__ out) {
  __shared__ unsigned short aggL[T_STEPS * 16 * 136];   // 34816 B
  __shared__ unsigned short Hb[2][16 * 136];            //  8704 B
  __shared__ unsigned short Sb[2][16 * 136];            //  8704 B
  int lane = threadIdx.x & 63;
  int nt = threadIdx.x >> 6;        // wave id: owns nodes {2nt,2nt+1} / col tile nt
  int q = lane >> 4, l15 = lane & 15;
  int tile = blockIdx.x;
  int row0 = tile * 16;
  int c = nt * 16 + l15;

  // ---- Phase A: scalar-decoded, branchless-validity, 8-chain quad walk ----
  {
    int kb0 = (row0 + nt * 2) * T_STEPS;
    int kb1 = kb0 + T_STEPS;
    int ke1 = kb1 + T_STEPS;
    int i0 = __builtin_amdgcn_readfirstlane(base[kb0] + bsum[kb0 >> 10]);
    int e0 = __builtin_amdgcn_readfirstlane(base[kb1] + bsum[kb1 >> 10]);
    int i1 = e0;                               // contiguous key ranges
    int e1 = __builtin_amdgcn_readfirstlane(base[ke1] + bsum[ke1 >> 10]);

    DECL8(ax0_); DECL8(ay0_); DECL8(ax1_); DECL8(ay1_);

    while (i0 < e0 || i1 < e1) {               // scalar control
      bool v00 = i0 < e0,     v01 = i0 + 1 < e0;
      bool v02 = i0 + 2 < e0, v03 = i0 + 3 < e0;
      bool v10 = i1 < e1,     v11 = i1 + 1 < e1;
      bool v12 = i1 + 2 < e1, v13 = i1 + 3 < e1;
      EDGE_LOAD(i0,     v00, m0a, m1a, ta);
      EDGE_LOAD(i0 + 1, v01, m0b, m1b, tb);
      EDGE_LOAD(i0 + 2, v02, m0c, m1c, tc);
      EDGE_LOAD(i0 + 3, v03, m0d, m1d, td);
      EDGE_LOAD(i1,     v10, m0e, m1e, te);
      EDGE_LOAD(i1 + 1, v11, m0f, m1f, tf);
      EDGE_LOAD(i1 + 2, v12, m0g, m1g, tg);
      EDGE_LOAD(i1 + 3, v13, m0h, m1h, th);
      ACC_SWITCH(ta, ax0_, ay0_, m0a, m1a);
      ACC_SWITCH(tb, ax0_, ay0_, m0b, m1b);
      ACC_SWITCH(tc, ax0_, ay0_, m0c, m1c);
      ACC_SWITCH(td, ax0_, ay0_, m0d, m1d);
      ACC_SWITCH(te, ax1_, ay1_, m0e, m1e);
      ACC_SWITCH(tf, ax1_, ay1_, m0f, m1f);
      ACC_SWITCH(tg, ax1_, ay1_, m0g, m1g);
      ACC_SWITCH(th, ax1_, ay1_, m0h, m1h);
      i0 = (i0 + 4 < e0) ? i0 + 4 : e0;
      i1 = (i1 + 4 < e1) ? i1 + 4 : e1;
    }

    int nl0 = nt * 2, nl1 = nt * 2 + 1;
    STROW8(nl0, ax0_, ay0_);
    STROW8(nl1, ax1_, ay1_);
  }
  __syncthreads();

  // ---- Phase B: encoder for ALL steps: H[t](:, nt-cols) as packed bf16 ----
  unsigned hpk[T_STEPS][2];
  {
    short8 wenc[4];
#pragma unroll
    for (int ks = 0; ks < 4; ks++)
      wenc[ks] = *(const short8*)(pack + ((nt * 4 + ks) * 64 + lane) * 8);
#pragma unroll
    for (int t = 0; t < T_STEPS; t++) {
      f32x4 acch = (f32x4){0.f, 0.f, 0.f, 0.f};
#pragma unroll
      for (int ks = 0; ks < 4; ks++) {
        short8 aA = *(const short8*)&aggL[(t * 16 + l15) * 136 + ks * 32 + q * 8];
        acch = __builtin_amdgcn_mfma_f32_16x16x32_bf16(aA, wenc[ks], acch, 0, 0, 0);
      }
      hpk[t][0] = cvt_pk_bf16(fast_tanh(acch[0]), fast_tanh(acch[1]));
      hpk[t][1] = cvt_pk_bf16(fast_tanh(acch[2]), fast_tanh(acch[3]));
    }
  }

  // recurrence weight B-fragments for this wave's nt
  short8 wz[4], uz[4], wh[4], uh[4];
#pragma unroll
  for (int ks = 0; ks < 4; ks++) {
    int fo = ((nt * 4 + ks) * 64 + lane) * 8;
    wz[ks] = *(const short8*)(pack + 16384 * 1 + fo);
    uz[ks] = *(const short8*)(pack + 16384 * 2 + fo);
    wh[ks] = *(const short8*)(pack + 16384 * 3 + fo);
    uh[ks] = *(const short8*)(pack + 16384 * 4 + fo);
  }
  float bzv = bz[c];
  float bhv = bh[c];

  f32x4 stC = (f32x4){0.f, 0.f, 0.f, 0.f};

  // ---- Phase C: GRU recurrence (R17 form: Hb kept + t=0 S-skip) ----
#pragma unroll
  for (int t = 0; t < T_STEPS; t++) {
    unsigned short* hB = Hb[t & 1];
    unsigned short* sB = Sb[t & 1];
    hB[(q * 4 + 0) * 136 + c] = (unsigned short)hpk[t][0];
    hB[(q * 4 + 1) * 136 + c] = (unsigned short)(hpk[t][0] >> 16);
    hB[(q * 4 + 2) * 136 + c] = (unsigned short)hpk[t][1];
    hB[(q * 4 + 3) * 136 + c] = (unsigned short)(hpk[t][1] >> 16);
    if (t > 0) {
      unsigned s01 = cvt_pk_bf16(stC[0], stC[1]);
      unsigned s23 = cvt_pk_bf16(stC[2], stC[3]);
      sB[(q * 4 + 0) * 136 + c] = (unsigned short)s01;
      sB[(q * 4 + 1) * 136 + c] = (unsigned short)(s01 >> 16);
      sB[(q * 4 + 2) * 136 + c] = (unsigned short)s23;
      sB[(q * 4 + 3) * 136 + c] = (unsigned short)(s23 >> 16);
    }
    __syncthreads();

    f32x4 accz = (f32x4){bzv, bzv, bzv, bzv};
    f32x4 accc = (f32x4){bhv, bhv, bhv, bhv};
    if (t > 0) {
#pragma unroll
      for (int ks = 0; ks < 4; ks++) {
        short8 hA = *(const short8*)&hB[l15 * 136 + ks * 32 + q * 8];
        short8 sA = *(const short8*)&sB[l15 * 136 + ks * 32 + q * 8];
        accz = __builtin_amdgcn_mfma_f32_16x16x32_bf16(hA, wz[ks], accz, 0, 0, 0);
        accz = __builtin_amdgcn_mfma_f32_16x16x32_bf16(sA, uz[ks], accz, 0, 0, 0);
        accc = __builtin_amdgcn_mfma_f32_16x16x32_bf16(hA, wh[ks], accc, 0, 0, 0);
        accc = __builtin_amdgcn_mfma_f32_16x16x32_bf16(sA, uh[ks], accc, 0, 0, 0);
      }
    } else {
#pragma unroll
      for (int ks = 0; ks < 4; ks++) {
        short8 hA = *(const short8*)&hB[l15 * 136 + ks * 32 + q * 8];
        accz = __builtin_amdgcn_mfma_f32_16x16x32_bf16(hA, wz[ks], accz, 0, 0, 0);
        accc = __builtin_amdgcn_mfma_f32_16x16x32_bf16(hA, wh[ks], accc, 0, 0, 0);
      }
    }
#pragma unroll
    for (int r = 0; r < 4; r++) {
      float z = fast_sig(accz[r]);
      float cc = fast_tanh(accc[r]);
      stC[r] = (1.f - z) * stC[r] + z * cc;
    }
  }

  // final state -> out (fp32, C-layout positions)
#pragma unroll
  for (int r = 0; r < 4; r++)
    out[(size_t)(row0 + q * 4 + r) * DIM + c] = stC[r];
}

extern "C" void kernel_launch(void* const* d_in, const int* in_sizes, int n_in,
                              void* d_out, int out_size, void* d_ws, size_t ws_size,
                              hipStream_t stream) {
  const int* eidx  = (const int*)d_in[0];
  const int* src   = eidx;
  const int* dst   = eidx + N_EDGES;
  const int* etype = (const int*)d_in[1];
  const int* etime = (const int*)d_in[2];
  const float* ew   = (const float*)d_in[3];
  const float* nemb = (const float*)d_in[4];
  const float* remb = (const float*)d_in[5];
  const float* Wenc = (const float*)d_in[6];
  const float* Wz   = (const float*)d_in[7];
  const float* Uz   = (const float*)d_in[8];
  const float* Wh   = (const float*)d_in[9];
  const float* Uh   = (const float*)d_in[10];
  const float* bz   = (const float*)d_in[11];
  const float* bh   = (const float*)d_in[12];
  // d_in[13] = num_times (constant 8 for this problem's fixed shapes)

  // ws layout: counts|cursor are contiguous so repack5 zeroes both in one pass
  int* counts = (int*)d_ws;                                        // SCAN_N
  int* cursor = counts + SCAN_N;                                   // KEYS
  int* bsum   = cursor + KEYS;                                     // 256
  int* base   = bsum + 256;                                        // SCAN_N
  uint2* ep2  = (uint2*)(base + ((SCAN_N + 1) & ~1));              // E, 8B-aligned
  unsigned short* pack = (unsigned short*)(ep2 + N_EDGES);         // 5*16384
  float* outp = (float*)d_out;

  repack5<<<(5 * 16384 + 255) / 256, 256, 0, stream>>>(Wenc, Wz, Uz, Wh, Uh,
                                                       pack, counts);
  hist_k<<<(N_EDGES + 255) / 256, 256, 0, stream>>>(dst, etime, counts);
  scan1_k<<<SCAN_BLKS, 256, 0, stream>>>(counts, base, bsum);
  scan2_k<<<1, 256, 0, stream>>>(bsum);
  fill_k<<<(N_EDGES + 255) / 256, 256, 0, stream>>>(src, dst, etype, etime, ew,
                                                    base, bsum, cursor, ep2);
  fused_recur<<<N_TILES, 512, 0, stream>>>(base, bsum, ep2, nemb, remb,
                                           pack, bz, bh, outp);
}